// Round 5
// baseline (1520.782 us; speedup 1.0000x reference)
//
#include <hip/hip_runtime.h>
#include <cstdint>
#include <cstddef>

#define B_ROWS 16384
#define S_ROWS 2048
#define D_DIM  512

typedef __attribute__((ext_vector_type(8))) short          s16x8;
typedef __attribute__((ext_vector_type(8))) unsigned short u16x8;
typedef __attribute__((ext_vector_type(4))) float          f32x4;

// ---------- bf16 split helpers ----------
static __device__ __forceinline__ unsigned short f2bf(float f) {
  unsigned int u = __builtin_bit_cast(unsigned int, f);
  u = (u + 0x7FFFu + ((u >> 16) & 1u)) >> 16;   // RNE
  return (unsigned short)u;
}
static __device__ __forceinline__ float bf2f(unsigned short h) {
  unsigned int u = ((unsigned int)h) << 16;
  return __builtin_bit_cast(float, u);
}
static __device__ __forceinline__ float mish_f(float z) {
  float sp = (z > 20.0f) ? z : log1pf(expf(z));
  return z * tanhf(sp);
}

static __device__ __forceinline__ f32x4 mfma16(s16x8 a, s16x8 b, f32x4 c) {
  return __builtin_amdgcn_mfma_f32_16x16x32_bf16(a, b, c, 0, 0, 0);
}

// async global->LDS, 16B per lane (dst is wave-uniform base; HW adds lane*16)
static __device__ __forceinline__ void gload16(unsigned short* lds_dst,
                                               const unsigned short* g_src) {
  __builtin_amdgcn_global_load_lds(
      (const __attribute__((address_space(1))) unsigned int*)g_src,
      (__attribute__((address_space(3))) unsigned int*)lds_dst,
      16, 0, 0);
}

// ---------- split fp32 -> (hi, lo) bf16 ----------
__global__ void split_kernel(const float* __restrict__ in,
                             unsigned short* __restrict__ hi,
                             unsigned short* __restrict__ lo, int n4) {
  const int stride = gridDim.x * blockDim.x;
  for (int i = blockIdx.x * blockDim.x + threadIdx.x; i < n4; i += stride) {
    const float4 v = ((const float4*)in)[i];
    float f[4] = {v.x, v.y, v.z, v.w};
    unsigned short hh[4], ll[4];
#pragma unroll
    for (int j = 0; j < 4; ++j) {
      hh[j] = f2bf(f[j]);
      ll[j] = f2bf(f[j] - bf2f(hh[j]));
    }
    ((ushort4*)hi)[i] = make_ushort4(hh[0], hh[1], hh[2], hh[3]);
    ((ushort4*)lo)[i] = make_ushort4(ll[0], ll[1], ll[2], ll[3]);
  }
}

// ---------- row squared-norms from (hi,lo), D=512, one wave per row ----------
__global__ void norm_kernel(const unsigned short* __restrict__ hi,
                            const unsigned short* __restrict__ lo,
                            float* __restrict__ out, int rows) {
  const int gw = (int)((blockIdx.x * blockDim.x + threadIdx.x) >> 6);
  const int l  = threadIdx.x & 63;
  if (gw >= rows) return;
  const size_t base = (size_t)gw * D_DIM + (size_t)l * 8;
  const u16x8 h8 = *(const u16x8*)(hi + base);
  const u16x8 l8 = *(const u16x8*)(lo + base);
  float s = 0.f;
#pragma unroll
  for (int j = 0; j < 8; ++j) {
    float v = bf2f(h8[j]) + bf2f(l8[j]);
    s += v * v;
  }
#pragma unroll
  for (int m = 32; m; m >>= 1) s += __shfl_xor(s, m, 64);
  if (l == 0) out[gw] = s;
}

// ---------- pipelined split-fp32 GEMM: C = epi(A @ B^T) ----------
// A [M,K], B [N,K] row-major as (hi,lo) bf16 pairs, expressed as a K_eff=3K
// bf16 GEMM: pass 0 = Ah.Bh, pass 1 = Ah.Bl, pass 2 = Al.Bh.
// 256x256 tile, 8 waves (2Mx4N), 512 threads, K advances in 32-wide slices.
// LDS: 4-slot ring x 32KB, counted vmcnt keeps 3 slices in flight.
//
// SYNC (R4 fix): vmcnt is PER-WAVE; slot data is staged by all 8 waves, so
// own-vmcnt alone does NOT make the slot readable (R3 tripwire race).
// Discipline per phase:  barrier -> ISSUE -> vmcnt(own slice landed)
//                        -> barrier (=> slice landed for ALL waves)
//                        -> ds_read -> MFMA -> lgkmcnt(0).
// vmcnt never drains to 0 in steady state (12 = 3 slices in flight).
//
// LDS slot layout (A part, same for B): pairRow pr (128 per part) = rows
// 2pr,2pr+1; row r's 16B k-chunk fg stored at position p = c8 ^ (pr&7),
// c8 = (r&1)*4 + fg  -> conflict-free ds_read_b128 (verified R2: 0 conflicts).
// Staging: linear LDS dst (global_load_lds), inverse permutation applied on
// the per-lane GLOBAL source address (rule #21).
//
// EPI: 0 bias+mish->split, 1 bias->split, 2 rbf->split, 3 mish->split, 4 plain->f32
template <int EPI>
__global__ __launch_bounds__(512, 2) void gemm8(
    const unsigned short* __restrict__ Ahi, const unsigned short* __restrict__ Alo,
    const unsigned short* __restrict__ Bhi, const unsigned short* __restrict__ Blo,
    const float* __restrict__ bias, const float* __restrict__ nrmA,
    const float* __restrict__ nrmB,
    unsigned short* __restrict__ Chi, unsigned short* __restrict__ Clo,
    float* __restrict__ Cf, int M, int N, int K) {
  __shared__ __align__(16) unsigned short lds[4 * 16384];  // 128 KiB

  const int tid = threadIdx.x;
  const int w = tid >> 6, l = tid & 63;
  const int wm = w >> 2, wn = w & 3;
  const int fr = l & 15, fg = l >> 4;

  // bijective XCD swizzle (m204) + tn-fast order
  const int nwg = (int)gridDim.x;
  const int q8 = nwg >> 3, r8 = nwg & 7;
  const int xcd = (int)blockIdx.x & 7, boff = (int)blockIdx.x >> 3;
  const int swz = (xcd < r8 ? xcd * (q8 + 1) : r8 * (q8 + 1) + (xcd - r8) * q8) + boff;
  const int nTn = N >> 8;
  const int tm = swz / nTn, tn = swz - tm * nTn;
  const int rowA0 = tm << 8, rowB0 = tn << 8;

  // ---- staging decode: entry d -> (row, k-offset) with inverse swizzle ----
  int rE[2], kcE[2];
#pragma unroll
  for (int e = 0; e < 2; ++e) {
    const int d = tid + e * 512;
    const int pr = d >> 3;
    const int c8 = (d & 7) ^ (pr & 7);
    rE[e]  = (pr << 1) | (c8 >> 2);
    kcE[e] = (c8 & 3) << 3;
  }
  size_t gofA0 = (size_t)(rowA0 + rE[0]) * (size_t)K + kcE[0];
  size_t gofA1 = (size_t)(rowA0 + rE[1]) * (size_t)K + kcE[1];
  size_t gofB0 = (size_t)(rowB0 + rE[0]) * (size_t)K + kcE[0];
  size_t gofB1 = (size_t)(rowB0 + rE[1]) * (size_t)K + kcE[1];
  const int wof = w << 9;  // wave*512 shorts (wave-uniform LDS base)

  // ---- issue-side state (issue runs 3 slices ahead of compute) ----
  int iss_slot = 0, iss_k = 0, iss_pass = 0;
  const unsigned short* pA = Ahi;
  const unsigned short* pB = Bhi;

#define ISSUE_UNIT()                                                     \
  do {                                                                   \
    unsigned short* sb = lds + (iss_slot << 14);                         \
    gload16(sb + wof,          pA + iss_k + gofA0);                      \
    gload16(sb + 4096 + wof,   pA + iss_k + gofA1);                      \
    gload16(sb + 8192 + wof,   pB + iss_k + gofB0);                      \
    gload16(sb + 12288 + wof,  pB + iss_k + gofB1);                      \
    iss_slot = (iss_slot + 1) & 3;                                       \
    iss_k += 32;                                                         \
    if (iss_k == K) {                                                    \
      iss_k = 0; ++iss_pass;                                             \
      pA = (iss_pass == 2) ? Alo : Ahi;                                  \
      pB = (iss_pass == 1) ? Blo : Bhi;                                  \
    }                                                                    \
  } while (0)

  // ---- fragment read addresses (per-lane constants) ----
  const int frh = fr >> 1;
  const int p = (((fr & 1) << 2) | fg) ^ (frh & 7);
  const int aab = ((wm << 6) + frh) * 128 + p * 16;            // A part base
  const int bbb = 16384 + ((wn << 5) + frh) * 128 + p * 16;    // B part base

  f32x4 acc[8][4];
#pragma unroll
  for (int i = 0; i < 8; ++i)
#pragma unroll
    for (int j = 0; j < 4; ++j) acc[i][j] = (f32x4){0.f, 0.f, 0.f, 0.f};

  const int nu = 3 * (K >> 5);

  // prologue: 3 slices in flight
  ISSUE_UNIT();
  ISSUE_UNIT();
  ISSUE_UNIT();

  for (int u = 0; u < nu; ++u) {
    __builtin_amdgcn_s_barrier();          // all waves' reads of slot (u-1)&3 retired
    if (u + 3 < nu) {
      ISSUE_UNIT();                        // into slot freed by phase u-1
      asm volatile("s_waitcnt vmcnt(12)" ::: "memory");  // OWN slice-u loads landed
    } else if (u == nu - 3) {
      asm volatile("s_waitcnt vmcnt(8)" ::: "memory");
    } else if (u == nu - 2) {
      asm volatile("s_waitcnt vmcnt(4)" ::: "memory");
    } else {
      asm volatile("s_waitcnt vmcnt(0)" ::: "memory");
    }
    __builtin_amdgcn_s_barrier();          // => slice u landed for ALL waves (R4 fix)

    const char* sc = (const char*)lds + ((size_t)(u & 3) << 15);
    s16x8 af[8], bf[4];
#pragma unroll
    for (int mi = 0; mi < 8; ++mi) af[mi] = *(const s16x8*)(sc + aab + (mi << 10));
#pragma unroll
    for (int ni = 0; ni < 4; ++ni) bf[ni] = *(const s16x8*)(sc + bbb + (ni << 10));

    __builtin_amdgcn_s_setprio(1);
#pragma unroll
    for (int mi = 0; mi < 8; ++mi)
#pragma unroll
      for (int ni = 0; ni < 4; ++ni)
        acc[mi][ni] = mfma16(af[mi], bf[ni], acc[mi][ni]);
    __builtin_amdgcn_s_setprio(0);
    asm volatile("s_waitcnt lgkmcnt(0)" ::: "memory");  // reads retired pre-barrier
  }
#undef ISSUE_UNIT

  // epilogue: C/D layout col = lane&15, row = (lane>>4)*4 + reg
  const int rowBase = rowA0 + (wm << 7);
  const int colBase = rowB0 + (wn << 6);
#pragma unroll
  for (int mi = 0; mi < 8; ++mi) {
#pragma unroll
    for (int ni = 0; ni < 4; ++ni) {
      const int col = colBase + ni * 16 + fr;
      float badd = 0.f;
      if constexpr (EPI == 0 || EPI == 1) badd = bias[col];
      float nB = 0.f;
      if constexpr (EPI == 2) nB = nrmB[col];
#pragma unroll
      for (int r = 0; r < 4; ++r) {
        const int row = rowBase + mi * 16 + fg * 4 + r;
        float v = acc[mi][ni][r];
        if constexpr (EPI == 0 || EPI == 1) v += badd;
        if constexpr (EPI == 2) {
          float d2 = nrmA[row] + nB - 2.f * v;
          v = expf(-sqrtf(fmaxf(d2, 0.f)));
        }
        if constexpr (EPI == 0 || EPI == 3) v = mish_f(v);
        const size_t o = (size_t)row * (size_t)N + (size_t)col;
        if constexpr (EPI == 4) {
          Cf[o] = v;
        } else {
          unsigned short h = f2bf(v);
          Chi[o] = h;
          Clo[o] = f2bf(v - bf2f(h));
        }
      }
    }
  }
}

template <int EPI>
static void launch_gemm(const unsigned short* Ahi, const unsigned short* Alo,
                        const unsigned short* Bhi, const unsigned short* Blo,
                        const float* bias, const float* nrmA, const float* nrmB,
                        unsigned short* Chi, unsigned short* Clo, float* Cf,
                        int M, int N, int K, hipStream_t stream) {
  dim3 grid((unsigned)((M >> 8) * (N >> 8)));
  gemm8<EPI><<<grid, dim3(512), 0, stream>>>(Ahi, Alo, Bhi, Blo, bias,
                                             nrmA, nrmB, Chi, Clo, Cf, M, N, K);
}

static int grid_for(int n4) {
  int g = (n4 + 255) / 256;
  return g > 4096 ? 4096 : g;
}

extern "C" void kernel_launch(void* const* d_in, const int* in_sizes, int n_in,
                              void* d_out, int out_size, void* d_ws, size_t ws_size,
                              hipStream_t stream) {
  const float* x       = (const float*)d_in[0];
  const float* samples = (const float*)d_in[1];
  const float* W1      = (const float*)d_in[2];
  const float* b1      = (const float*)d_in[3];
  const float* W2      = (const float*)d_in[4];
  const float* b2      = (const float*)d_in[5];
  const float* Wn1     = (const float*)d_in[6];
  const float* Wn2     = (const float*)d_in[7];
  float* outF = (float*)d_out;

  if (ws_size < 167845888ull) return;  // clean visible failure if ws too small

  // ---- d_out region (134,217,728 B) doubles as scratch ----
  char* ob = (char*)d_out;
  unsigned short* xhi  = (unsigned short*)(ob + 0);          // dead after dml(x) L1
  unsigned short* xlo  = (unsigned short*)(ob + 16777216);
  unsigned short* t1hi = (unsigned short*)(ob + 33554432);   // dead after dml(x) L2
  unsigned short* t1lo = (unsigned short*)(ob + 50331648);
  unsigned short* t2hi = (unsigned short*)(ob + 67108864);   // dead after dml(s) L2
  unsigned short* t2lo = (unsigned short*)(ob + 69206016);
  unsigned short* Khi  = (unsigned short*)(ob + 0);          // written by RBF gemm
  unsigned short* Klo  = (unsigned short*)(ob + 67108864);   // dead before final write

  // ---- workspace ----
  char* wb = (char*)d_ws;
  unsigned short* hhi  = (unsigned short*)(wb + 0);          // written at nystrom L1
  unsigned short* hlo  = (unsigned short*)(wb + 67108864);
  //   early overlay inside h region (all dead before h is written):
  unsigned short* xdhi = (unsigned short*)(wb + 0);
  unsigned short* xdlo = (unsigned short*)(wb + 16777216);
  unsigned short* snhi = (unsigned short*)(wb + 33554432);
  unsigned short* snlo = (unsigned short*)(wb + 35651584);
  unsigned short* samhi= (unsigned short*)(wb + 37748736);
  unsigned short* samlo= (unsigned short*)(wb + 39845888);
  unsigned short* W1hi = (unsigned short*)(wb + 41943040);
  unsigned short* W1lo = (unsigned short*)(wb + 42467328);
  unsigned short* W2hi = (unsigned short*)(wb + 42991616);
  unsigned short* W2lo = (unsigned short*)(wb + 43515904);
  //   persistent region:
  unsigned short* Wn1hi= (unsigned short*)(wb + 134217728);
  unsigned short* Wn1lo= (unsigned short*)(wb + 142606336);
  unsigned short* Wn2hi= (unsigned short*)(wb + 150994944);
  unsigned short* Wn2lo= (unsigned short*)(wb + 159383552);
  float* nx            = (float*)(wb + 167772160);
  float* ns            = (float*)(wb + 167837696);

  const dim3 tpb(256);

  // split inputs into (hi, lo) bf16
  {
    int n4;
    n4 = B_ROWS * D_DIM / 4;
    split_kernel<<<grid_for(n4), tpb, 0, stream>>>(x, xhi, xlo, n4);
    n4 = S_ROWS * D_DIM / 4;
    split_kernel<<<grid_for(n4), tpb, 0, stream>>>(samples, samhi, samlo, n4);
    n4 = D_DIM * D_DIM / 4;
    split_kernel<<<grid_for(n4), tpb, 0, stream>>>(W1, W1hi, W1lo, n4);
    split_kernel<<<grid_for(n4), tpb, 0, stream>>>(W2, W2hi, W2lo, n4);
    n4 = S_ROWS * S_ROWS / 4;
    split_kernel<<<grid_for(n4), tpb, 0, stream>>>(Wn1, Wn1hi, Wn1lo, n4);
    split_kernel<<<grid_for(n4), tpb, 0, stream>>>(Wn2, Wn2hi, Wn2lo, n4);
  }

  // dml(x): t1 = mish(x@W1^T + b1); xd = t1@W2^T + b2
  launch_gemm<0>(xhi, xlo, W1hi, W1lo, b1, nullptr, nullptr, t1hi, t1lo, nullptr,
                 B_ROWS, D_DIM, D_DIM, stream);
  launch_gemm<1>(t1hi, t1lo, W2hi, W2lo, b2, nullptr, nullptr, xdhi, xdlo, nullptr,
                 B_ROWS, D_DIM, D_DIM, stream);
  // dml(samples)
  launch_gemm<0>(samhi, samlo, W1hi, W1lo, b1, nullptr, nullptr, t2hi, t2lo, nullptr,
                 S_ROWS, D_DIM, D_DIM, stream);
  launch_gemm<1>(t2hi, t2lo, W2hi, W2lo, b2, nullptr, nullptr, snhi, snlo, nullptr,
                 S_ROWS, D_DIM, D_DIM, stream);

  // row norms (from the same hi+lo values the MFMA consumes)
  norm_kernel<<<dim3(B_ROWS / 4), tpb, 0, stream>>>(xdhi, xdlo, nx, B_ROWS);
  norm_kernel<<<dim3(S_ROWS / 4), tpb, 0, stream>>>(snhi, snlo, ns, S_ROWS);

  // K = exp(-sqrt(max(nx + ns - 2 * xd@sn^T, 0)))
  launch_gemm<2>(xdhi, xdlo, snhi, snlo, nullptr, nx, ns, Khi, Klo, nullptr,
                 B_ROWS, S_ROWS, D_DIM, stream);

  // h = mish(K@Wn1^T)
  launch_gemm<3>(Khi, Klo, Wn1hi, Wn1lo, nullptr, nullptr, nullptr, hhi, hlo, nullptr,
                 B_ROWS, S_ROWS, S_ROWS, stream);

  // out = h@Wn2^T
  launch_gemm<4>(hhi, hlo, Wn2hi, Wn2lo, nullptr, nullptr, nullptr, nullptr, nullptr,
                 outF, B_ROWS, S_ROWS, S_ROWS, stream);
}